// Round 3
// baseline (10292.715 us; speedup 1.0000x reference)
//
#include <hip/hip_runtime.h>
#include <math.h>

// DrugGraphConv: 5000 graphs x 100 nodes x 400 edges, 5 TAGConv(K=2) layers
// DIMS = [74,70,65,60,55,37], gated softmax pooling per graph.
// One 512-thread block per graph. All state in LDS (64.0 KB -> 2 blocks/CU,
// 16 waves/CU). h rows padded to stride 76 so GEMM reads are ds_read_b128.
// Propagation is CSR-gather (counting sort built once per block) -- no fp32
// atomics, norm scaling fused. GEMM: 2 output cols x NPT nodes per thread,
// k vectorized by 4 -> 8 FMAs per LDS b128 read.
//
// R2 lesson: __launch_bounds__(512,4) clamped VGPRs to 64 -> acc arrays
// spilled to scratch (16 GB WRITE_SIZE, 27 GB HBM traffic/launch). Bound
// relaxed to (512,2): occupancy is LDS-limited to 2 blocks/CU anyway, so a
// ~128-VGPR allocation costs nothing and kills the spills.

constexpr int NODES  = 100;
constexpr int EDGES  = 400;
constexpr int STRIDE = 76;     // padded feature stride (multiple of 4)
constexpr int NTHR   = 512;

struct Smem {
    float bufA[NODES * STRIDE + 4];   // 30,416 B (pad keeps b128 clamp-safe)
    float bufB[NODES * STRIDE + 4];   // 30,416 B
    int   csr_src[EDGES];             //  1,600 B
    int   row_start[NODES + 1];       //    404 B
    int   cnt[NODES];                 //    400 B (degree, then CSR fill)
    float nrm[NODES];                 //    400 B
    float gate[NODES];                //    400 B   => 64,036 B total
};

// out[n][:] = nrm[n] * sum_{e: dst==n} nrm[src_e] * in[src_e][:]
template<int D_IN>
__device__ __forceinline__ void propagate(const float* __restrict__ in,
                                          float* __restrict__ outb,
                                          const int* __restrict__ csr_src,
                                          const int* __restrict__ row_start,
                                          const float* __restrict__ nrm,
                                          int tid)
{
    constexpr int CH = (D_IN + 3) / 4;           // float4 chunks per row
    for (int t = tid; t < NODES * CH; t += NTHR) {
        int n = t / CH;                          // compile-time divisor
        int c = t - n * CH;
        int beg = row_start[n], end = row_start[n + 1];
        float ax = 0.f, ay = 0.f, az = 0.f, aw = 0.f;
        for (int e = beg; e < end; ++e) {
            int s = csr_src[e];
            float sc = nrm[s];
            const float4 v = *(const float4*)&in[s * STRIDE + 4 * c];
            ax = fmaf(sc, v.x, ax); ay = fmaf(sc, v.y, ay);
            az = fmaf(sc, v.z, az); aw = fmaf(sc, v.w, aw);
        }
        float sn = nrm[n];
        float4 o = { ax * sn, ay * sn, az * sn, aw * sn };
        *(float4*)&outb[n * STRIDE + 4 * c] = o;
    }
}

template<int D_IN, int D_OUT>
__device__ __forceinline__ void tag_layer(Smem& sm,
                                          const float* __restrict__ W,
                                          const float* __restrict__ Bv,
                                          int tid)
{
    constexpr int CF  = D_IN / 4;                // full k-chunks
    constexpr int KR  = D_IN % 4;                // tail k's
    constexpr int P   = (D_OUT + 1) / 2;         // cols per half
    constexpr int NG  = NTHR / P;                // node groups
    constexpr int NPT = (NODES + NG - 1) / NG;   // nodes per thread

    const int col  = tid % P;
    const int grp  = tid / P;
    const bool has2 = (col + P) < D_OUT;
    const int col2 = has2 ? col + P : col;       // safe duplicate if !has2

    // clamped row byte-offsets (speculative reads of row 99, discarded at write)
    int roff[NPT];
#pragma unroll
    for (int j = 0; j < NPT; ++j) {
        int n = grp * NPT + j;
        if (n > NODES - 1) n = NODES - 1;
        roff[j] = n * STRIDE;
    }

    float acc0[NPT], acc1[NPT];
#pragma unroll
    for (int j = 0; j < NPT; ++j) { acc0[j] = 0.f; acc1[j] = 0.f; }

    auto gblock = [&](const float* __restrict__ buf, int b) {
        const float* __restrict__ Wb = W + b * D_IN * D_OUT;
        for (int cc = 0; cc < CF; ++cc) {
            float w0[4], w1[4];
#pragma unroll
            for (int i = 0; i < 4; ++i) {
                int k = 4 * cc + i;
                w0[i] = Wb[k * D_OUT + col];
                w1[i] = Wb[k * D_OUT + col2];
            }
#pragma unroll
            for (int j = 0; j < NPT; ++j) {
                const float4 h4 = *(const float4*)&buf[roff[j] + 4 * cc];
                acc0[j] = fmaf(h4.x, w0[0], acc0[j]);
                acc0[j] = fmaf(h4.y, w0[1], acc0[j]);
                acc0[j] = fmaf(h4.z, w0[2], acc0[j]);
                acc0[j] = fmaf(h4.w, w0[3], acc0[j]);
                acc1[j] = fmaf(h4.x, w1[0], acc1[j]);
                acc1[j] = fmaf(h4.y, w1[1], acc1[j]);
                acc1[j] = fmaf(h4.z, w1[2], acc1[j]);
                acc1[j] = fmaf(h4.w, w1[3], acc1[j]);
            }
        }
        if constexpr (KR > 0) {
            float w0[KR], w1[KR];
#pragma unroll
            for (int i = 0; i < KR; ++i) {
                int k = 4 * CF + i;
                w0[i] = Wb[k * D_OUT + col];
                w1[i] = Wb[k * D_OUT + col2];
            }
#pragma unroll
            for (int j = 0; j < NPT; ++j) {
                const float4 h4 = *(const float4*)&buf[roff[j] + 4 * CF];
                const float hv[4] = { h4.x, h4.y, h4.z, h4.w };
#pragma unroll
                for (int i = 0; i < KR; ++i) {
                    acc0[j] = fmaf(hv[i], w0[i], acc0[j]);
                    acc1[j] = fmaf(hv[i], w1[i], acc1[j]);
                }
            }
        }
    };

    // feats block 0: h itself (bufA)
    gblock(sm.bufA, 0);
    // hop 1: bufA -> bufB (bufB's old content is dead; bufA reads race-free)
    propagate<D_IN>(sm.bufA, sm.bufB, sm.csr_src, sm.row_start, sm.nrm, tid);
    __syncthreads();
    // feats block 1: hop1 (bufB)
    gblock(sm.bufB, 1);
    // hop 2: bufB -> bufA (all reads of bufA finished before sync above)
    propagate<D_IN>(sm.bufB, sm.bufA, sm.csr_src, sm.row_start, sm.nrm, tid);
    __syncthreads();
    // feats block 2: hop2 (bufA)
    gblock(sm.bufA, 2);
    __syncthreads();   // all reads of bufA done before h-overwrite

    const float b0v = Bv[col];
    const float b1v = Bv[col2];
#pragma unroll
    for (int j = 0; j < NPT; ++j) {
        int n = grp * NPT + j;
        if (n < NODES) {
            sm.bufA[n * STRIDE + col] = fmaxf(acc0[j] + b0v, 0.f);
            if (has2) sm.bufA[n * STRIDE + col + P] = fmaxf(acc1[j] + b1v, 0.f);
        }
    }
    // zero pad cols [D_OUT, 4*ceil(D_OUT/4)) so next layer's b128 tail is clean
    constexpr int PADW = (4 - (D_OUT & 3)) & 3;
    if constexpr (PADW > 0) {
        for (int t = tid; t < NODES * PADW; t += NTHR) {
            int n = t / PADW;
            int c = t - n * PADW;
            sm.bufA[n * STRIDE + D_OUT + c] = 0.f;
        }
    }
    __syncthreads();
}

__global__ __launch_bounds__(NTHR, 2)
void drug_graph_conv_kernel(
    const float* __restrict__ x,
    const int*   __restrict__ src,
    const int*   __restrict__ dst,
    const float* __restrict__ W0, const float* __restrict__ b0,
    const float* __restrict__ W1, const float* __restrict__ b1,
    const float* __restrict__ W2, const float* __restrict__ b2,
    const float* __restrict__ W3, const float* __restrict__ b3,
    const float* __restrict__ W4, const float* __restrict__ b4,
    const float* __restrict__ gate_w, const float* __restrict__ gate_b,
    float* __restrict__ out)
{
    __shared__ Smem sm;
    const int g     = blockIdx.x;
    const int tid   = threadIdx.x;
    const int nbase = g * NODES;

    // ---- stage x into bufA (stride 76) as float2; zero pad cols 74,75 ----
    const float2* __restrict__ x2 = (const float2*)(x + nbase * 74);
    for (int t = tid; t < NODES * 37; t += NTHR) {
        int n  = t / 37;
        int k2 = t - n * 37;
        *(float2*)&sm.bufA[n * STRIDE + 2 * k2] = x2[t];
    }
    for (int t = tid; t < NODES * 2; t += NTHR) {
        int n = t >> 1;
        sm.bufA[n * STRIDE + 74 + (t & 1)] = 0.f;
    }

    // ---- degree count ----
    if (tid < NODES) sm.cnt[tid] = 0;
    __syncthreads();
    int es = 0, ed = 0;
    const bool ethr = tid < EDGES;
    if (ethr) {
        es = src[g * EDGES + tid] - nbase;
        ed = dst[g * EDGES + tid] - nbase;
        atomicAdd(&sm.cnt[ed], 1);
    }
    __syncthreads();

    // ---- norm + CSR row offsets (wave-0 shuffle scan over 100 degrees) ----
    if (tid < NODES) sm.nrm[tid] = rsqrtf((float)max(sm.cnt[tid], 1));
    if (tid < 64) {
        int v1 = (tid < NODES) ? sm.cnt[tid] : 0;
        int l2 = tid + 64;
        int v2 = (l2 < NODES) ? sm.cnt[l2] : 0;
        int s1 = v1;
#pragma unroll
        for (int d = 1; d < 64; d <<= 1) {
            int t2 = __shfl_up(s1, d, 64);
            if (tid >= d) s1 += t2;
        }
        int tot1 = __shfl(s1, 63, 64);
        int s2 = v2;
#pragma unroll
        for (int d = 1; d < 64; d <<= 1) {
            int t2 = __shfl_up(s2, d, 64);
            if (tid >= d) s2 += t2;
        }
        s2 += tot1;
        if (tid == 0) sm.row_start[0] = 0;
        sm.row_start[tid + 1] = s1;
        if (l2 < NODES) sm.row_start[l2 + 1] = s2;
    }
    __syncthreads();
    if (tid < NODES) sm.cnt[tid] = 0;   // reuse as CSR fill cursor
    __syncthreads();
    if (ethr) {
        int pos = atomicAdd(&sm.cnt[ed], 1);
        sm.csr_src[sm.row_start[ed] + pos] = es;
    }
    __syncthreads();

    // ---- 5 TAGConv layers ----
    tag_layer<74, 70>(sm, W0, b0, tid);
    tag_layer<70, 65>(sm, W1, b1, tid);
    tag_layer<65, 60>(sm, W2, b2, tid);
    tag_layer<60, 55>(sm, W3, b3, tid);
    tag_layer<55, 37>(sm, W4, b4, tid);
    // bufA: final h, 100 x 37, stride 76

    // ---- gate + softmax + pool ----
    if (tid < NODES) {
        float s = gate_b[0];
#pragma unroll
        for (int k = 0; k < 37; ++k)
            s = fmaf(sm.bufA[tid * STRIDE + k], gate_w[k], s);
        sm.gate[tid] = s;
    }
    __syncthreads();
    if (tid < 64) {
        float v1 = (tid < NODES) ? sm.gate[tid] : -INFINITY;
        float v2 = (tid + 64 < NODES) ? sm.gate[tid + 64] : -INFINITY;
        float m = fmaxf(v1, v2);
#pragma unroll
        for (int d = 32; d; d >>= 1) m = fmaxf(m, __shfl_xor(m, d, 64));
        float e1 = (tid < NODES) ? __expf(v1 - m) : 0.f;
        float e2 = (tid + 64 < NODES) ? __expf(v2 - m) : 0.f;
        float z = e1 + e2;
#pragma unroll
        for (int d = 32; d; d >>= 1) z += __shfl_xor(z, d, 64);
        float inv = 1.f / z;
        if (tid < NODES) sm.gate[tid] = e1 * inv;
        if (tid + 64 < NODES) sm.gate[tid + 64] = e2 * inv;
    }
    __syncthreads();
    if (tid < 37) {
        float p = 0.f;
        for (int n = 0; n < NODES; ++n)
            p = fmaf(sm.gate[n], sm.bufA[n * STRIDE + tid], p);
        out[g * 37 + tid] = p;
    }
}

extern "C" void kernel_launch(void* const* d_in, const int* in_sizes, int n_in,
                              void* d_out, int out_size, void* d_ws, size_t ws_size,
                              hipStream_t stream) {
    const float* x   = (const float*)d_in[0];
    const int*   src = (const int*)  d_in[1];
    const int*   dst = (const int*)  d_in[2];
    // d_in[3] = graph_ids (implicit: node / 100) -- unused
    const float* W0 = (const float*)d_in[4];  const float* b0 = (const float*)d_in[5];
    const float* W1 = (const float*)d_in[6];  const float* b1 = (const float*)d_in[7];
    const float* W2 = (const float*)d_in[8];  const float* b2 = (const float*)d_in[9];
    const float* W3 = (const float*)d_in[10]; const float* b3 = (const float*)d_in[11];
    const float* W4 = (const float*)d_in[12]; const float* b4 = (const float*)d_in[13];
    const float* gw = (const float*)d_in[14]; const float* gb = (const float*)d_in[15];
    float* out = (float*)d_out;

    drug_graph_conv_kernel<<<5000, NTHR, 0, stream>>>(
        x, src, dst, W0, b0, W1, b1, W2, b2, W3, b3, W4, b4, gw, gb, out);
}

// Round 4
// 3494.707 us; speedup vs baseline: 2.9452x; 2.9452x over previous
//
#include <hip/hip_runtime.h>
#include <math.h>

// DrugGraphConv: 5000 graphs x 100 nodes x 400 edges, 5 TAGConv(K=2) layers
// DIMS = [74,70,65,60,55,37], gated softmax pooling per graph.
//
// R3 lesson: per-lane W loads + big unrolled register tiles = spills (12.5 GB
// scratch writes) and stalls; only 3.5% of the fp32-VALU ceiling used.
//
// R4 design: one 512-thread block per graph, LDS-resident state (64.8 KB).
//  - Wave layout: 8 waves = 2 node-halves x 4 col-groups. lane = node.
//    tid>>6 forced wave-uniform via readfirstlane => W/bias indices are
//    uniform => compiler emits SCALAR loads (s_load) for all weights; FMAs
//    are v_fma(vgpr, sgpr) -- no VGPR pressure from W, scalar pipe prefetches.
//  - h stored at stride 77 (odd): lane=node b32 reads/writes are bank-conflict
//    free (lane*77 mod 32 covers all banks 2x).
//  - GEMM inner loop: 1 ds_read_b32 + CW<=18 FMAs per k. acc[<=18] per thread.
//  - Propagation: CSR gather (counting sort once per block), norm fused, b32.

constexpr int NODES  = 100;
constexpr int EDGES  = 400;
constexpr int STRIDE = 77;     // odd => conflict-free lane=node column access
constexpr int NTHR   = 512;

struct Smem {
    float bufA[NODES * STRIDE];   // 30,800 B
    float bufB[NODES * STRIDE];   // 30,800 B
    int   csr_src[EDGES];         //  1,600 B
    int   row_start[NODES + 1];   //    404 B
    int   cnt[NODES];             //    400 B
    float nrm[NODES];             //    400 B
    float gate[NODES];            //    400 B   => 64,804 B
};

// out[n][:] = nrm[n] * sum_{e: dst==n} nrm[src_e] * in[src_e][:]
template<int D_IN>
__device__ __forceinline__ void propagate(const float* __restrict__ in,
                                          float* __restrict__ outb,
                                          const int* __restrict__ csr_src,
                                          const int* __restrict__ row_start,
                                          const float* __restrict__ nrm,
                                          int tid)
{
    for (int t = tid; t < NODES * D_IN; t += NTHR) {
        int n = t / D_IN;                 // compile-time divisor
        int d = t - n * D_IN;
        int beg = row_start[n], end = row_start[n + 1];
        float a = 0.f;
        for (int e = beg; e < end; ++e) {
            int s = csr_src[e];
            a = fmaf(nrm[s], in[s * STRIDE + d], a);
        }
        outb[n * STRIDE + d] = a * nrm[n];
    }
}

template<int D_IN, int D_OUT>
__device__ __forceinline__ void tag_layer(Smem& sm,
                                          const float* __restrict__ W,
                                          const float* __restrict__ Bv,
                                          int tid)
{
    constexpr int CW = (D_OUT + 3) / 4;         // cols per col-group (<=18)

    const int wave    = __builtin_amdgcn_readfirstlane(tid >> 6); // 0..7 uniform
    const int lane    = tid & 63;
    const int cgrp    = wave >> 1;              // 0..3  (uniform)
    const int nhalf   = wave & 1;               // 0..1  (uniform)
    const int node    = nhalf * 64 + lane;
    const int nclamp  = node > NODES - 1 ? NODES - 1 : node;
    const int colbase = cgrp * CW;              // uniform

    float acc[CW];
#pragma unroll
    for (int j = 0; j < CW; ++j) acc[j] = 0.f;

    auto gblock = [&](const float* __restrict__ buf, int b) {
        const float* __restrict__ Wb = W + b * D_IN * D_OUT;
        const float* __restrict__ hrow = buf + nclamp * STRIDE;
#pragma unroll 2
        for (int k = 0; k < D_IN; ++k) {
            float hv = hrow[k];                 // ds_read_b32, conflict-free
#pragma unroll
            for (int j = 0; j < CW; ++j) {
                int c = colbase + j;            // uniform
                if (c > D_OUT - 1) c = D_OUT - 1;
                acc[j] = fmaf(hv, Wb[k * D_OUT + c], acc[j]);  // W via SGPR
            }
        }
    };

    // feats block 0: h (bufA); then hop1 bufA->bufB (bufB dead, no race)
    gblock(sm.bufA, 0);
    propagate<D_IN>(sm.bufA, sm.bufB, sm.csr_src, sm.row_start, sm.nrm, tid);
    __syncthreads();
    // feats block 1: hop1 (bufB); then hop2 bufB->bufA (bufA reads all done)
    gblock(sm.bufB, 1);
    propagate<D_IN>(sm.bufB, sm.bufA, sm.csr_src, sm.row_start, sm.nrm, tid);
    __syncthreads();
    // feats block 2: hop2 (bufA)
    gblock(sm.bufA, 2);
    __syncthreads();    // all reads of bufA complete before h' overwrite

    if (node < NODES) {
#pragma unroll
        for (int j = 0; j < CW; ++j) {
            int c = colbase + j;
            if (c < D_OUT)
                sm.bufA[node * STRIDE + c] = fmaxf(acc[j] + Bv[c], 0.f);
        }
    }
    __syncthreads();
}

__global__ __launch_bounds__(NTHR, 2)
void drug_graph_conv_kernel(
    const float* __restrict__ x,
    const int*   __restrict__ src,
    const int*   __restrict__ dst,
    const float* __restrict__ W0, const float* __restrict__ b0,
    const float* __restrict__ W1, const float* __restrict__ b1,
    const float* __restrict__ W2, const float* __restrict__ b2,
    const float* __restrict__ W3, const float* __restrict__ b3,
    const float* __restrict__ W4, const float* __restrict__ b4,
    const float* __restrict__ gate_w, const float* __restrict__ gate_b,
    float* __restrict__ out)
{
    __shared__ Smem sm;
    const int g     = blockIdx.x;
    const int tid   = threadIdx.x;
    const int nbase = g * NODES;

    // ---- stage x (100 x 74) into bufA at stride 77 (coalesced global reads) ----
    for (int t = tid; t < NODES * 74; t += NTHR) {
        int n = t / 74;
        int d = t - n * 74;
        sm.bufA[n * STRIDE + d] = x[nbase * 74 + t];
    }

    // ---- degree count ----
    if (tid < NODES) sm.cnt[tid] = 0;
    __syncthreads();
    int es = 0, ed = 0;
    const bool ethr = tid < EDGES;
    if (ethr) {
        es = src[g * EDGES + tid] - nbase;
        ed = dst[g * EDGES + tid] - nbase;
        atomicAdd(&sm.cnt[ed], 1);
    }
    __syncthreads();

    // ---- norm + CSR row offsets (wave-0 shuffle scan over 100 degrees) ----
    if (tid < NODES) sm.nrm[tid] = rsqrtf((float)max(sm.cnt[tid], 1));
    if (tid < 64) {
        int v1 = (tid < NODES) ? sm.cnt[tid] : 0;
        int l2 = tid + 64;
        int v2 = (l2 < NODES) ? sm.cnt[l2] : 0;
        int s1 = v1;
#pragma unroll
        for (int d = 1; d < 64; d <<= 1) {
            int t2 = __shfl_up(s1, d, 64);
            if (tid >= d) s1 += t2;
        }
        int tot1 = __shfl(s1, 63, 64);
        int s2 = v2;
#pragma unroll
        for (int d = 1; d < 64; d <<= 1) {
            int t2 = __shfl_up(s2, d, 64);
            if (tid >= d) s2 += t2;
        }
        s2 += tot1;
        if (tid == 0) sm.row_start[0] = 0;
        sm.row_start[tid + 1] = s1;
        if (l2 < NODES) sm.row_start[l2 + 1] = s2;
    }
    __syncthreads();
    if (tid < NODES) sm.cnt[tid] = 0;   // reuse as CSR fill cursor
    __syncthreads();
    if (ethr) {
        int pos = atomicAdd(&sm.cnt[ed], 1);
        sm.csr_src[sm.row_start[ed] + pos] = es;
    }
    __syncthreads();

    // ---- 5 TAGConv layers ----
    tag_layer<74, 70>(sm, W0, b0, tid);
    tag_layer<70, 65>(sm, W1, b1, tid);
    tag_layer<65, 60>(sm, W2, b2, tid);
    tag_layer<60, 55>(sm, W3, b3, tid);
    tag_layer<55, 37>(sm, W4, b4, tid);
    // bufA: final h, 100 x 37, stride 77

    // ---- gate + softmax + pool ----
    if (tid < NODES) {
        float s = gate_b[0];
#pragma unroll
        for (int k = 0; k < 37; ++k)
            s = fmaf(sm.bufA[tid * STRIDE + k], gate_w[k], s);
        sm.gate[tid] = s;
    }
    __syncthreads();
    if (tid < 64) {
        float v1 = (tid < NODES) ? sm.gate[tid] : -INFINITY;
        float v2 = (tid + 64 < NODES) ? sm.gate[tid + 64] : -INFINITY;
        float m = fmaxf(v1, v2);
#pragma unroll
        for (int d = 32; d; d >>= 1) m = fmaxf(m, __shfl_xor(m, d, 64));
        float e1 = (tid < NODES) ? __expf(v1 - m) : 0.f;
        float e2 = (tid + 64 < NODES) ? __expf(v2 - m) : 0.f;
        float z = e1 + e2;
#pragma unroll
        for (int d = 32; d; d >>= 1) z += __shfl_xor(z, d, 64);
        float inv = 1.f / z;
        if (tid < NODES) sm.gate[tid] = e1 * inv;
        if (tid + 64 < NODES) sm.gate[tid + 64] = e2 * inv;
    }
    __syncthreads();
    if (tid < 37) {
        float p = 0.f;
        for (int n = 0; n < NODES; ++n)
            p = fmaf(sm.gate[n], sm.bufA[n * STRIDE + tid], p);
        out[g * 37 + tid] = p;
    }
}

extern "C" void kernel_launch(void* const* d_in, const int* in_sizes, int n_in,
                              void* d_out, int out_size, void* d_ws, size_t ws_size,
                              hipStream_t stream) {
    const float* x   = (const float*)d_in[0];
    const int*   src = (const int*)  d_in[1];
    const int*   dst = (const int*)  d_in[2];
    // d_in[3] = graph_ids (implicit: node / 100) -- unused
    const float* W0 = (const float*)d_in[4];  const float* b0 = (const float*)d_in[5];
    const float* W1 = (const float*)d_in[6];  const float* b1 = (const float*)d_in[7];
    const float* W2 = (const float*)d_in[8];  const float* b2 = (const float*)d_in[9];
    const float* W3 = (const float*)d_in[10]; const float* b3 = (const float*)d_in[11];
    const float* W4 = (const float*)d_in[12]; const float* b4 = (const float*)d_in[13];
    const float* gw = (const float*)d_in[14]; const float* gb = (const float*)d_in[15];
    float* out = (float*)d_out;

    drug_graph_conv_kernel<<<5000, NTHR, 0, stream>>>(
        x, src, dst, W0, b0, W1, b1, W2, b2, W3, b3, W4, b4, gw, gb, out);
}